// Round 1
// baseline (530.502 us; speedup 1.0000x reference)
//
#include <hip/hip_runtime.h>

#define CROP_H 14
#define CROP_W 14
#define NBOX   512
#define CH     256
#define IMH    200
#define IMW    200
#define PLANE   (IMH * IMW)                 // 40000 floats per channel plane
#define NPOS    (CROP_H * CROP_W)           // 196 sample positions per box
#define PER_BOX (CH * NPOS)                 // 50176
#define CGROUPS 8                           // channel groups per box
#define CPG     (CH / CGROUPS)              // 32 channels per block

// Position-resident threads: thread t < 196 owns one (gy,gx) sample point of
// its box. Indices, bilinear weights and validity are computed ONCE, then a
// 32-channel loop runs a pure {2 loads, 7 FMA-ish ops, 1 store} body.
// Grid (box=x fastest, cgroup=y): 4096 blocks, 8 resident/CU -> the live
// window spans ~2 channel-groups = 164 MB of image < 256 MB L3, so cross-box
// reuse of image lines is L3-resident. Nontemporal stores keep L2 for image.
__global__ __launch_bounds__(256, 8) void CropAndResize_60146722013533_kernel(
    const float* __restrict__ image,
    const float* __restrict__ boxes,
    const int*   __restrict__ box_idx,
    float*       __restrict__ out)
{
    const int n  = blockIdx.x;          // box index (fastest dispatch dim)
    const int cg = blockIdx.y;          // channel group
    const int t  = threadIdx.x;
    if (t >= NPOS) return;              // no barriers below; safe early-exit

    const int gy = t / CROP_W;
    const int gx = t - gy * CROP_W;

    // Box params are block-uniform -> scalar loads.
    const float by1 = boxes[n * 4 + 0];
    const float bx1 = boxes[n * 4 + 1];
    const float by2 = boxes[n * 4 + 2];
    const float bx2 = boxes[n * 4 + 3];
    const int   b   = box_idx[n];

    // Same arithmetic (same order) as the verified previous kernel.
    const float h_scale = (by2 - by1) * (float)(IMH - 1) / (float)(CROP_H - 1);
    const float w_scale = (bx2 - bx1) * (float)(IMW - 1) / (float)(CROP_W - 1);
    const float in_y = by1 * (float)(IMH - 1) + (float)gy * h_scale;
    const float in_x = bx1 * (float)(IMW - 1) + (float)gx * w_scale;

    const bool valid = (in_y >= 0.0f) && (in_y <= (float)(IMH - 1)) &&
                       (in_x >= 0.0f) && (in_x <= (float)(IMW - 1));

    const float yf = floorf(in_y);
    const float xf = floorf(in_x);
    const float ly = in_y - yf;
    const float lx = in_x - xf;

    const int y0  = (int)fminf(fmaxf(yf,          0.0f), (float)(IMH - 1));
    const int y1i = (int)fminf(fmaxf(ceilf(in_y), 0.0f), (float)(IMH - 1));
    const int x0  = (int)fminf(fmaxf(xf,          0.0f), (float)(IMW - 1));
    const int x1i = (int)fminf(fmaxf(ceilf(in_x), 0.0f), (float)(IMW - 1));

    // tl/tr (and bl/br) are adjacent in x: load each pair as one 8B access
    // anchored at xb = min(x0, W-2); then x0 and x1i are both in {xb, xb+1}.
    const int  xb    = (x0 < IMW - 2) ? x0 : (IMW - 2);
    const int  offt  = y0  * IMW + xb;   // per-lane, channel-invariant
    const int  offb  = y1i * IMW + xb;
    const bool selt0 = (x0  == xb);
    const bool selt1 = (x1i == xb);

    const float* plane = image + (size_t)(b * CH + cg * CPG) * (size_t)PLANE;
    float*       o     = out + (size_t)n * PER_BOX + (size_t)(cg * CPG) * NPOS + t;

    #pragma unroll 4
    for (int c = 0; c < CPG; ++c) {
        float2 vt, vb;
        __builtin_memcpy(&vt, plane + offt, 8);
        __builtin_memcpy(&vb, plane + offb, 8);

        const float tl = selt0 ? vt.x : vt.y;
        const float tr = selt1 ? vt.x : vt.y;
        const float bl = selt0 ? vb.x : vb.y;
        const float br = selt1 ? vb.x : vb.y;

        const float top = tl + (tr - tl) * lx;
        const float bot = bl + (br - bl) * lx;
        float val = top + (bot - top) * ly;
        if (!valid) val = 0.0f;

        __builtin_nontemporal_store(val, o);

        plane += PLANE;   // uniform SGPR-side increment
        o     += NPOS;    // stores stay coalesced across lanes per c
    }
}

extern "C" void kernel_launch(void* const* d_in, const int* in_sizes, int n_in,
                              void* d_out, int out_size, void* d_ws, size_t ws_size,
                              hipStream_t stream) {
    const float* image   = (const float*)d_in[0];
    const float* boxes   = (const float*)d_in[1];
    const int*   box_idx = (const int*)d_in[2];
    float* out = (float*)d_out;

    dim3 grid(NBOX, CGROUPS, 1);   // x = box (fastest), y = channel group
    dim3 block(256, 1, 1);
    CropAndResize_60146722013533_kernel<<<grid, block, 0, stream>>>(image, boxes, box_idx, out);
}